// Round 1
// baseline (129.170 us; speedup 1.0000x reference)
//
#include <hip/hip_runtime.h>

// cvmm: out[m] = x[m] @ w[sel[m]]
// x: [M,64] f32, sel: [M] i32, w: [8,64,64] f32, out: [M,64] f32
//
// R6: block-local expert sort + operand-swapped MFMA.
// Previous (R5, 42us kernel): masked 8-expert MFMA with all-expert B pinned in
// 64 AGPRs -> 128 regs/wave -> 16 waves/CU cap; 64 MFMA + 256 cndmask per
// chunk-wave of which 1/8 is real work; 16 scalar dword C-stores. All pipes
// <31% => latency/occupancy bound at 2.4 TB/s.
// This version:
//  - prep kernel packs w into MFMA A-operand fragment layout (bf16, 64KB in
//    d_ws): per-tile B-operand load = 2 L2-hot dwordx4 (no register pin).
//  - main: block = 128 tokens. x loaded CONTIGUOUSLY (8x dwordx4/thread,
//    issued first so the sort hides load latency). Stable ballot/popcount
//    sort of the 128 tokens by expert -> sortLds[slot] = token | expert<<8.
//    Staging to LDS bf16 (XOR-granule swizzle) stays in original row order;
//    only the MFMA *read* side permutes rows.
//  - sorted slots => ~1.9 experts per 16-token m-tile: uniform tiles take the
//    no-mask fast path (2 MFMA); boundary tiles loop e in [elo,ehi] masked.
//  - operand swap: acc = mfma(Wfrag, Xfrag) -> D[row=n][col=token]; lane holds
//    4 consecutive n for one token -> single global_store_dwordx4 per tile.
//  - ~50 VGPR, no AGPR, LDS 16.6KB -> __launch_bounds__(256,8), grid 2048
//    = 8 blocks/CU = 32 waves/CU.

typedef __bf16 bf16x8 __attribute__((ext_vector_type(8)));
typedef __bf16 bf16x4 __attribute__((ext_vector_type(4)));
typedef float  floatx4 __attribute__((ext_vector_type(4)));

// ---- prep: pack w into A-operand fragment layout --------------------------
// entry id = ((e*2 + t)*4 + nt)*64 + lane ; content (q=lane>>4, l16=lane&15):
//   f[j] = w[e][t*32 + q*8 + j][nt*16 + l16]   (j = 0..7)
__global__ __launch_bounds__(256) void wpack_kernel(
    const float* __restrict__ w, bf16x8* __restrict__ wp)
{
    const int id   = blockIdx.x * 256 + threadIdx.x;   // 0..4095
    const int lane = id & 63;
    const int nt   = (id >> 6) & 3;
    const int t    = (id >> 8) & 1;
    const int e    = id >> 9;
    const int q = lane >> 4, l16 = lane & 15;
    const float* src = w + (((e * 64) + t * 32 + q * 8) * 64) + nt * 16 + l16;
    bf16x8 f;
#pragma unroll
    for (int j = 0; j < 8; ++j) f[j] = (__bf16)src[j * 64];
    wp[id] = f;
}

// ---- main -----------------------------------------------------------------
__global__ __launch_bounds__(256, 8) void cvmm_kernel(
    const float* __restrict__ x,
    const int* __restrict__ sel,
    const bf16x8* __restrict__ wp,
    float* __restrict__ out)
{
    // x tile: 128 rows x 128B bf16, 16B granules XOR-swizzled by row:
    //   phys(row, g) = row*128 + ((g ^ (row&7))<<4)
    __shared__ __align__(16) unsigned char xls[128 * 128];
    __shared__ unsigned int sortLds[128];   // slot -> token | expert<<8
    __shared__ int wcLds[16];               // [wave<2][expert] counts

    const int T    = threadIdx.x;
    const int lane = T & 63;
    const int wv   = T >> 6;     // 0..3 -> n-tile
    const int q    = lane >> 4;  // 0..3
    const int l16  = lane & 15;
    const int n0   = wv << 4;

    const long tok0 = (long)blockIdx.x * 128;

    // 1) issue x loads immediately (contiguous, perfectly coalesced).
    //    reg i: row = i*16 + (T>>4), cols [(T&15)*4, +4)
    const float* xb = x + tok0 * 64;
    floatx4 R[8];
#pragma unroll
    for (int i = 0; i < 8; ++i)
        R[i] = *(const floatx4*)(xb + i * 1024 + 4 * T);

    // 2) stable sort of 128 tokens by expert (waves 0,1 own one token each).
    int s = 0, myrank = 0;
    if (T < 128) {
        s = sel[tok0 + T];
        const unsigned long long lt = (1ull << lane) - 1;
#pragma unroll
        for (int e = 0; e < 8; ++e) {
            unsigned long long m = __ballot(s == e);
            if (s == e) myrank = __popcll(m & lt);
            if (lane == 0) wcLds[wv * 8 + e] = __popcll(m);
        }
    }
    __syncthreads();
    if (T < 128) {
        int bb = 0;
#pragma unroll
        for (int e2 = 0; e2 < 8; ++e2) {
            const int tot = wcLds[e2] + wcLds[8 + e2];
            if (e2 < s) bb += tot;
        }
        const int wb = (wv == 1) ? wcLds[s] : 0;   // wave0's count for my expert
        sortLds[bb + wb + myrank] = (unsigned)T | ((unsigned)s << 8);
    }

    // 3) stage x -> LDS bf16, swizzled (original row order; vmcnt wait on R
    //    here, largely hidden under the sort above).
    const int wrow = T >> 4;
    const int g    = (T & 15) >> 1;
    const int half = (T & 1) * 8;
#pragma unroll
    for (int i = 0; i < 8; ++i) {
        const int row = i * 16 + wrow;
        bf16x4 v;
        v[0] = (__bf16)R[i][0]; v[1] = (__bf16)R[i][1];
        v[2] = (__bf16)R[i][2]; v[3] = (__bf16)R[i][3];
        *(bf16x4*)(xls + row * 128 + (((g) ^ (row & 7)) << 4) + half) = v;
    }
    __syncthreads();   // covers sortLds + xls

    // 4) compute 8 m-tiles. Operand-swapped: acc = mfma(Wfrag, Xfrag) ->
    //    lane(q,l16) holds out[tok(l16)][n0 + q*4 + r], r=0..3.
    bf16x8 zf;
#pragma unroll
    for (int j = 0; j < 8; ++j) zf[j] = (__bf16)0.0f;

    const bf16x8* wpw = wp + wv * 64 + lane;   // + e*512 + t*256

#pragma unroll
    for (int i = 0; i < 8; ++i) {
        const unsigned u = sortLds[i * 16 + l16];
        const int tokL = (int)(u & 255u);
        const int el   = (int)(u >> 8);
        const bf16x8 af0 = *(const bf16x8*)(xls + tokL * 128 + (((q)     ^ (tokL & 7)) << 4));
        const bf16x8 af1 = *(const bf16x8*)(xls + tokL * 128 + (((q + 4) ^ (tokL & 7)) << 4));
        const int elo = __builtin_amdgcn_readfirstlane(el);  // lane 0 == l16 0
        const int ehi = __builtin_amdgcn_readlane(el, 15);

        floatx4 acc = {0.0f, 0.0f, 0.0f, 0.0f};
        if (elo == ehi) {              // uniform-expert tile: no masking
            const bf16x8 wf0 = wpw[elo * 512];
            const bf16x8 wf1 = wpw[elo * 512 + 256];
            acc = __builtin_amdgcn_mfma_f32_16x16x32_bf16(wf0, af0, acc, 0, 0, 0);
            acc = __builtin_amdgcn_mfma_f32_16x16x32_bf16(wf1, af1, acc, 0, 0, 0);
        } else {                       // boundary tile: small masked loop
            for (int e = elo; e <= ehi; ++e) {
                const bf16x8 wf0 = wpw[e * 512];
                const bf16x8 wf1 = wpw[e * 512 + 256];
                const bool ok = (el == e);
                const bf16x8 am0 = ok ? af0 : zf;
                const bf16x8 am1 = ok ? af1 : zf;
                acc = __builtin_amdgcn_mfma_f32_16x16x32_bf16(wf0, am0, acc, 0, 0, 0);
                acc = __builtin_amdgcn_mfma_f32_16x16x32_bf16(wf1, am1, acc, 0, 0, 0);
            }
        }
        float* op = out + (tok0 + tokL) * 64 + n0 + (q << 2);
        *(floatx4*)op = acc;           // one dwordx4 per tile
    }
}

extern "C" void kernel_launch(void* const* d_in, const int* in_sizes, int n_in,
                              void* d_out, int out_size, void* d_ws, size_t ws_size,
                              hipStream_t stream) {
    const float* x   = (const float*)d_in[0];
    const int*   sel = (const int*)d_in[1];
    const float* w   = (const float*)d_in[2];
    float*       out = (float*)d_out;

    const int M = in_sizes[0] / 64;                 // 262144
    bf16x8* wp = (bf16x8*)d_ws;                     // 64 KB packed fragments

    wpack_kernel<<<16, 256, 0, stream>>>(w, wp);
    cvmm_kernel<<<M / 128, 256, 0, stream>>>(x, sel, wp, out);
}

// Round 2
// 125.828 us; speedup vs baseline: 1.0266x; 1.0266x over previous
//
#include <hip/hip_runtime.h>

// cvmm: out[m] = x[m] @ w[sel[m]]
// x: [M,64] f32, sel: [M] i32, w: [8,64,64] f32, out: [M,64] f32
//
// R7: persistent chunked pipeline + sorted-slot LDS rows.
// R6 post-mortem: sort/operand-swap fixed compute (VALU 12%, Mfma 3%) but
// dur stayed 43.5us @ 2.4TB/s. VGPR=28 < 32 needed for R[8] proves the
// compiler sank the x-loads (MLP ~2-3/thread); single-shot blocks (1 chunk,
// then exit) left every wave eating full loaded-HBM latency + a long drain
// (Occ 57%). This version:
//  - 512 blocks x 4 chunks x 128 tokens; 2 blocks/CU; double-buffered LDS.
//  - depth-2 register prefetch (RA/RB, 64 VGPR of in-flight loads = 128KB/CU
//    outstanding); loads re-issued immediately after each barrier.
//  - raw s_barrier with manual lgkmcnt(0) only (no vmcnt drain) so prefetch
//    loads stay in flight across barriers. All global->LDS data moves via
//    registers, so vmcnt correctness is compiler-tracked (counted waits).
//  - sort (wave 0, in-register ballot/popc) produces inv[token]->slot; the
//    STAGE writes token rows into sorted slot rows. Compute reads STATIC
//    rows i*16+l16 with static XOR swizzle -> bank-floor LDS reads, and no
//    sortLds -> ds_read dependency (sortLds only feeds store addr + experts).
//  - uniform-expert tiles: 2 MFMA, no mask; boundary tiles: short masked loop.
//  - wpack kernel (as R6) packs w into fragment layout in d_ws.

typedef __bf16 bf16x8 __attribute__((ext_vector_type(8)));
typedef __bf16 bf16x4 __attribute__((ext_vector_type(4)));
typedef float  floatx4 __attribute__((ext_vector_type(4)));

#define NCHUNK 4
#define CT 128                  // tokens per chunk
#define BLK_TOK (NCHUNK * CT)   // 512 tokens per block

// ---- prep: pack w into A-operand fragment layout --------------------------
// entry id = ((e*2 + t)*4 + nt)*64 + lane ; content (q=lane>>4, l16=lane&15):
//   f[j] = w[e][t*32 + q*8 + j][nt*16 + l16]   (j = 0..7)
__global__ __launch_bounds__(256) void wpack_kernel(
    const float* __restrict__ w, bf16x8* __restrict__ wp)
{
    const int id   = blockIdx.x * 256 + threadIdx.x;   // 0..4095
    const int lane = id & 63;
    const int nt   = (id >> 6) & 3;
    const int t    = (id >> 8) & 1;
    const int e    = id >> 9;
    const int q = lane >> 4, l16 = lane & 15;
    const float* src = w + (((e * 64) + t * 32 + q * 8) * 64) + nt * 16 + l16;
    bf16x8 f;
#pragma unroll
    for (int j = 0; j < 8; ++j) f[j] = (__bf16)src[j * 64];
    wp[id] = f;
}

// Raw barrier: drain LDS ops only; vmcnt (register prefetch) stays in flight.
#define BAR() do {                                         \
    __builtin_amdgcn_sched_barrier(0);                     \
    asm volatile("s_waitcnt lgkmcnt(0)" ::: "memory");     \
    __builtin_amdgcn_s_barrier();                          \
    __builtin_amdgcn_sched_barrier(0);                     \
} while (0)

// ---- main -----------------------------------------------------------------
__global__ __launch_bounds__(256, 2) void cvmm_kernel(
    const float* __restrict__ x,
    const int* __restrict__ sel,
    const bf16x8* __restrict__ wp,
    float* __restrict__ out)
{
    // x tile (per buffer): 128 slot-rows x 128 B bf16; 16-B granules
    // XOR-swizzled: phys(row, g) = row*128 + ((g ^ (row&7))<<4)
    __shared__ __align__(16) unsigned char xls[2][16384];
    __shared__ unsigned int sortLds[2][128];   // slot -> token | expert<<8
    __shared__ unsigned int invLds[2][128];    // token -> slot

    const int T    = threadIdx.x;
    const int lane = T & 63;
    const int wv   = T >> 6;     // 0..3 -> n-tile
    const int q    = lane >> 4;  // 0..3
    const int l16  = lane & 15;
    const int n0   = wv << 4;

    const int wrow = T >> 4;        // 0..15 (row-within-16 in staging)
    const int gl   = (T & 15) >> 1; // staging granule 0..7
    const int half = (T & 1) * 8;   // 8-B half within granule
    const int roffA = ((q)     ^ (l16 & 7)) << 4;   // static read swizzle
    const int roffB = ((q + 4) ^ (l16 & 7)) << 4;

    const long base = (long)blockIdx.x * BLK_TOK;

    bf16x8 zf;
#pragma unroll
    for (int j = 0; j < 8; ++j) zf[j] = (__bf16)0.0f;

    const bf16x8* wpw = wp + wv * 64 + lane;   // + e*512 + t*256

    // ---- prologue: sel first (so sort never waits on x), then x c0, c1
    int sA0 = 0, sA1 = 0, sB0 = 0, sB1 = 0;
    if (wv == 0) {
        const int* sp = sel + base;
        sA0 = sp[lane];      sA1 = sp[64 + lane];
        sB0 = sp[CT + lane]; sB1 = sp[CT + 64 + lane];
    }
    floatx4 RA[8], RB[8];
    {
        const float* xc = x + base * 64;
#pragma unroll
        for (int i = 0; i < 8; ++i)
            RA[i] = *(const floatx4*)(xc + i * 1024 + 4 * T);
#pragma unroll
        for (int i = 0; i < 8; ++i)
            RB[i] = *(const floatx4*)(xc + CT * 64 + i * 1024 + 4 * T);
    }

#define CHUNK_BODY(c, RX, sX0, sX1)                                          \
    {                                                                        \
        const int buf = (c) & 1;                                             \
        /* sort: wave 0, in-register; writes slot tables */                  \
        if (wv == 0) {                                                       \
            const unsigned long long lt = (1ull << lane) - 1;                \
            int slot0 = 0, slot1 = 0, pref = 0;                              \
            _Pragma("unroll")                                                \
            for (int e = 0; e < 8; ++e) {                                    \
                unsigned long long m0 = __ballot(sX0 == e);                  \
                unsigned long long m1 = __ballot(sX1 == e);                  \
                if (sX0 == e) slot0 = pref + __popcll(m0 & lt);              \
                if (sX1 == e) slot1 = pref + __popcll(m0) + __popcll(m1 & lt);\
                pref += __popcll(m0) + __popcll(m1);                         \
            }                                                                \
            invLds[buf][lane]      = (unsigned)slot0;                        \
            invLds[buf][64 + lane] = (unsigned)slot1;                        \
            sortLds[buf][slot0] = (unsigned)lane        | ((unsigned)sX0 << 8); \
            sortLds[buf][slot1] = (unsigned)(64 + lane) | ((unsigned)sX1 << 8); \
        }                                                                    \
        BAR();                                                               \
        /* stage regs -> LDS: token row -> sorted slot row, swizzled */      \
        {                                                                    \
            unsigned char* lb = xls[buf];                                    \
            _Pragma("unroll")                                                \
            for (int i = 0; i < 8; ++i) {                                    \
                const int slot = (int)invLds[buf][i * 16 + wrow];            \
                bf16x4 v;                                                    \
                v[0] = (__bf16)RX[i][0]; v[1] = (__bf16)RX[i][1];            \
                v[2] = (__bf16)RX[i][2]; v[3] = (__bf16)RX[i][3];            \
                *(bf16x4*)(lb + slot * 128 + ((gl ^ (slot & 7)) << 4) + half) = v; \
            }                                                                \
        }                                                                    \
        /* prefetch sel for chunk c+2 (before x so sort never waits on x) */ \
        if (wv == 0 && (c) + 2 < NCHUNK) {                                   \
            const int* sp = sel + base + ((c) + 2) * CT;                     \
            sX0 = sp[lane]; sX1 = sp[64 + lane];                             \
        }                                                                    \
        BAR();                                                               \
        /* re-issue x prefetch immediately after barrier: in flight across   \
           the whole compute phase + next chunk's sort/stage */              \
        if ((c) + 2 < NCHUNK) {                                              \
            const float* xc = x + (base + ((c) + 2) * CT) * 64;              \
            _Pragma("unroll")                                                \
            for (int i = 0; i < 8; ++i)                                      \
                RX[i] = *(const floatx4*)(xc + i * 1024 + 4 * T);            \
        }                                                                    \
        /* compute 8 m-tiles; rows are STATIC (slot order) */                \
        {                                                                    \
            const unsigned char* lb = xls[buf];                              \
            const long ct0 = base + (c) * CT;                                \
            _Pragma("unroll")                                                \
            for (int i = 0; i < 8; ++i) {                                    \
                const unsigned u = sortLds[buf][i * 16 + l16];               \
                const int tokL = (int)(u & 255u);                            \
                const int el   = (int)(u >> 8);                              \
                const int rb2  = (i * 16 + l16) * 128;                       \
                const bf16x8 af0 = *(const bf16x8*)(lb + rb2 + roffA);       \
                const bf16x8 af1 = *(const bf16x8*)(lb + rb2 + roffB);       \
                const int elo = __builtin_amdgcn_readfirstlane(el);          \
                const int ehi = __builtin_amdgcn_readlane(el, 15);           \
                floatx4 acc = {0.0f, 0.0f, 0.0f, 0.0f};                      \
                if (elo == ehi) {                                            \
                    acc = __builtin_amdgcn_mfma_f32_16x16x32_bf16(           \
                              wpw[elo * 512],       af0, acc, 0, 0, 0);      \
                    acc = __builtin_amdgcn_mfma_f32_16x16x32_bf16(           \
                              wpw[elo * 512 + 256], af1, acc, 0, 0, 0);      \
                } else {                                                     \
                    for (int e = elo; e <= ehi; ++e) {                       \
                        const bool ok = (el == e);                           \
                        acc = __builtin_amdgcn_mfma_f32_16x16x32_bf16(       \
                                  wpw[e * 512],       ok ? af0 : zf, acc, 0, 0, 0); \
                        acc = __builtin_amdgcn_mfma_f32_16x16x32_bf16(       \
                                  wpw[e * 512 + 256], ok ? af1 : zf, acc, 0, 0, 0); \
                    }                                                        \
                }                                                            \
                float* op = out + (ct0 + tokL) * 64 + n0 + (q << 2);         \
                *(floatx4*)op = acc;                                         \
            }                                                                \
        }                                                                    \
    }

    CHUNK_BODY(0, RA, sA0, sA1)
    CHUNK_BODY(1, RB, sB0, sB1)
    CHUNK_BODY(2, RA, sA0, sA1)
    CHUNK_BODY(3, RB, sB0, sB1)
#undef CHUNK_BODY
}

extern "C" void kernel_launch(void* const* d_in, const int* in_sizes, int n_in,
                              void* d_out, int out_size, void* d_ws, size_t ws_size,
                              hipStream_t stream) {
    const float* x   = (const float*)d_in[0];
    const int*   sel = (const int*)d_in[1];
    const float* w   = (const float*)d_in[2];
    float*       out = (float*)d_out;

    const int M = in_sizes[0] / 64;                 // 262144
    bf16x8* wp = (bf16x8*)d_ws;                     // 64 KB packed fragments

    wpack_kernel<<<16, 256, 0, stream>>>(w, wp);
    cvmm_kernel<<<M / BLK_TOK, 256, 0, stream>>>(x, sel, wp, out);
}

// Round 3
// 121.417 us; speedup vs baseline: 1.0639x; 1.0363x over previous
//
#include <hip/hip_runtime.h>

// cvmm: out[m] = x[m] @ w[sel[m]]
// x: [M,64] f32, sel: [M] i32, w: [8,64,64] f32, out: [M,64] f32
//
// R8: full-line store path. R5/R6/R7 (three different structures) all pinned
// at 2.3-2.4 TB/s with all pipes <15% busy -> effective-BW limit of the
// access pattern, not latency/issue. Common denominator: out stored as
// scattered <=64B segments (16 token rows x 64B per store instr after the
// sort permute). fillBufferAligned (full-line stores) hits 6.5 TB/s on the
// same data volume. Fix:
//  - compute tiles ds_write their acc granule (16B = out[tok][4n..4n+3]) into
//    an LDS out-buffer at the ORIGINAL token row (inverse permute on the LDS
//    write side); after a barrier the block streams obuf->out as lane-linear
//    1KB-contiguous full-line stores (fill-kernel regime).
//  - obuf row stride 272B (17 granules) -> token-random ds_writes spread over
//    banks; stream-side reads are exactly uniform (8 lanes/granule-slot).
//  - all 8 experts' W fragments pinned in regs at prologue (16 coalesced
//    L2-hot loads from the packed table); per-tile expert selection is a
//    wave-uniform skip-loop over the unrolled 8 -> no per-tile dependent
//    global load chain (R6/R7's other serial-latency term).
//  - one-shot 128-token blocks (2048 blocks), sorted-slot static LDS rows as
//    R7 (bank-floor reads, sortLds only feeds expert range + out row).
// LDS 52.2KB -> 3 blocks/CU; VGPR ~130 -> 12 waves/CU.

typedef __bf16 bf16x8 __attribute__((ext_vector_type(8)));
typedef __bf16 bf16x4 __attribute__((ext_vector_type(4)));
typedef float  floatx4 __attribute__((ext_vector_type(4)));

#define CT 128   // tokens per block

// ---- prep: pack w into A-operand fragment layout --------------------------
// entry id = ((e*2 + t)*4 + nt)*64 + lane ; content (q=lane>>4, l16=lane&15):
//   f[j] = w[e][t*32 + q*8 + j][nt*16 + l16]   (j = 0..7)
__global__ __launch_bounds__(256) void wpack_kernel(
    const float* __restrict__ w, bf16x8* __restrict__ wp)
{
    const int id   = blockIdx.x * 256 + threadIdx.x;   // 0..4095
    const int lane = id & 63;
    const int nt   = (id >> 6) & 3;
    const int t    = (id >> 8) & 1;
    const int e    = id >> 9;
    const int q = lane >> 4, l16 = lane & 15;
    const float* src = w + (((e * 64) + t * 32 + q * 8) * 64) + nt * 16 + l16;
    bf16x8 f;
#pragma unroll
    for (int j = 0; j < 8; ++j) f[j] = (__bf16)src[j * 64];
    wp[id] = f;
}

// ---- main -----------------------------------------------------------------
__global__ __launch_bounds__(256, 3) void cvmm_kernel(
    const float* __restrict__ x,
    const int* __restrict__ sel,
    const bf16x8* __restrict__ wp,
    float* __restrict__ out)
{
    // x tile: 128 slot-rows x 128B bf16; granules XOR-swizzled by row.
    __shared__ __align__(16) unsigned char xls[CT * 128];     // 16 KB
    // out staging: 128 token-rows x 272B (16 granules + 1 pad granule).
    __shared__ __align__(16) unsigned char obuf[CT * 272];    // 34 KB
    __shared__ unsigned int sortLds[CT];   // slot -> token | expert<<8
    __shared__ unsigned int invLds[CT];    // token -> slot

    const int T    = threadIdx.x;
    const int lane = T & 63;
    const int wv   = T >> 6;     // 0..3 -> n-tile
    const int q    = lane >> 4;  // 0..3
    const int l16  = lane & 15;

    const long tok0 = (long)blockIdx.x * CT;

    // 1) sel first (sort depends only on it)
    int s0 = 0, s1 = 0;
    if (wv == 0) {
        s0 = sel[tok0 + lane];
        s1 = sel[tok0 + 64 + lane];
    }

    // 2) x loads: contiguous dwordx4, reg i holds token row i*16 + (T>>4)
    const float* xb = x + tok0 * 64;
    floatx4 R[8];
#pragma unroll
    for (int i = 0; i < 8; ++i)
        R[i] = *(const floatx4*)(xb + i * 1024 + 4 * T);

    // 3) pin all 8 experts' W fragments (L2-hot packed table, coalesced)
    const bf16x8* wpw = wp + wv * 64 + lane;
    floatx4 bfp[8][2];
#pragma unroll
    for (int e = 0; e < 8; ++e) {
#pragma unroll
        for (int t = 0; t < 2; ++t)
            bfp[e][t] = __builtin_bit_cast(floatx4, wpw[e * 512 + t * 256]);
    }
#pragma unroll
    for (int e = 0; e < 8; ++e) {
        asm volatile("" : "+v"(bfp[e][0]), "+v"(bfp[e][1]));
    }

    // 4) sort 128 tokens by expert (wave 0; 2 tokens/lane), stable
    if (wv == 0) {
        const unsigned long long lt = (1ull << lane) - 1;
        int slot0 = 0, slot1 = 0, pref = 0;
#pragma unroll
        for (int e = 0; e < 8; ++e) {
            unsigned long long m0 = __ballot(s0 == e);
            unsigned long long m1 = __ballot(s1 == e);
            if (s0 == e) slot0 = pref + __popcll(m0 & lt);
            if (s1 == e) slot1 = pref + __popcll(m0) + __popcll(m1 & lt);
            pref += __popcll(m0) + __popcll(m1);
        }
        invLds[lane]      = (unsigned)slot0;
        invLds[64 + lane] = (unsigned)slot1;
        sortLds[slot0] = (unsigned)lane        | ((unsigned)s0 << 8);
        sortLds[slot1] = (unsigned)(64 + lane) | ((unsigned)s1 << 8);
    }
    __syncthreads();

    // 5) stage x -> LDS bf16: token row -> sorted slot row, XOR swizzle
    {
        const int wrow = T >> 4;
        const int gl   = (T & 15) >> 1;
        const int half = (T & 1) * 8;
#pragma unroll
        for (int i = 0; i < 8; ++i) {
            const int slot = (int)invLds[i * 16 + wrow];
            bf16x4 v;
            v[0] = (__bf16)R[i][0]; v[1] = (__bf16)R[i][1];
            v[2] = (__bf16)R[i][2]; v[3] = (__bf16)R[i][3];
            *(bf16x4*)(xls + slot * 128 + ((gl ^ (slot & 7)) << 4) + half) = v;
        }
    }
    __syncthreads();

    // 6) compute 8 m-tiles; static slot rows; acc -> obuf at ORIGINAL token
    {
        const int roffA = ((q)     ^ (l16 & 7)) << 4;
        const int roffB = ((q + 4) ^ (l16 & 7)) << 4;
        bf16x8 zf;
#pragma unroll
        for (int j = 0; j < 8; ++j) zf[j] = (__bf16)0.0f;

#pragma unroll
        for (int i = 0; i < 8; ++i) {
            const unsigned u = sortLds[i * 16 + l16];
            const int tokL = (int)(u & 255u);
            const int el   = (int)(u >> 8);
            const int rb   = (i * 16 + l16) * 128;
            const bf16x8 af0 = *(const bf16x8*)(xls + rb + roffA);
            const bf16x8 af1 = *(const bf16x8*)(xls + rb + roffB);
            const int elo = __builtin_amdgcn_readfirstlane(el);  // lane 0 == slot min
            const int ehi = __builtin_amdgcn_readlane(el, 15);

            floatx4 acc = {0.0f, 0.0f, 0.0f, 0.0f};
#pragma unroll
            for (int e = 0; e < 8; ++e) {
                if (e >= elo && e <= ehi) {          // wave-uniform guard
                    const bool ok = (el == e);       // per-lane (boundary only)
                    acc = __builtin_amdgcn_mfma_f32_16x16x32_bf16(
                              __builtin_bit_cast(bf16x8, bfp[e][0]),
                              ok ? af0 : zf, acc, 0, 0, 0);
                    acc = __builtin_amdgcn_mfma_f32_16x16x32_bf16(
                              __builtin_bit_cast(bf16x8, bfp[e][1]),
                              ok ? af1 : zf, acc, 0, 0, 0);
                }
            }
            // acc = out[tokL][n0+4q .. n0+4q+3] = granule (wv*4+q) of row tokL
            *(floatx4*)(obuf + tokL * 272 + (wv * 4 + q) * 16) = acc;
        }
    }
    __syncthreads();

    // 7) stream obuf -> out: lane-linear, 1KB contiguous per wave instr
    {
        float* og = out + tok0 * 64;
#pragma unroll
        for (int i = 0; i < 8; ++i) {
            const int G = i * 256 + T;               // granule 0..2047
            const floatx4 v = *(const floatx4*)(obuf + (G >> 4) * 272 + (G & 15) * 16);
            *(floatx4*)(og + G * 4) = v;
        }
    }
}

extern "C" void kernel_launch(void* const* d_in, const int* in_sizes, int n_in,
                              void* d_out, int out_size, void* d_ws, size_t ws_size,
                              hipStream_t stream) {
    const float* x   = (const float*)d_in[0];
    const int*   sel = (const int*)d_in[1];
    const float* w   = (const float*)d_in[2];
    float*       out = (float*)d_out;

    const int M = in_sizes[0] / 64;                 // 262144
    bf16x8* wp = (bf16x8*)d_ws;                     // 64 KB packed fragments

    wpack_kernel<<<16, 256, 0, stream>>>(w, wp);
    cvmm_kernel<<<M / CT, 256, 0, stream>>>(x, sel, wp, out);
}